// Round 4
// baseline (777.187 us; speedup 1.0000x reference)
//
#include <hip/hip_runtime.h>
#include <math.h>

#define EMB 128
#define NR 6
#define NS 7
#define NB 8
#define TL 128   // triplets per block in the MFMA bilinear kernel

typedef __attribute__((ext_vector_type(8))) short short8;   // 8 bf16 = 4 VGPR
typedef __attribute__((ext_vector_type(4))) float floatx4;  // MFMA C/D

__device__ __forceinline__ short f2bf(float f) {  // fp32 -> bf16 RNE
  unsigned int u = __float_as_uint(f);
  u = u + 0x7fff + ((u >> 16) & 1);
  return (short)(u >> 16);
}

// ---------------------------------------------------------------------------
__global__ void zero_kernel(float4* __restrict__ p, long n4) {
  long i = (long)blockIdx.x * blockDim.x + threadIdx.x;
  long stride = (long)gridDim.x * blockDim.x;
  float4 z; z.x = z.y = z.z = z.w = 0.f;
  for (; i < n4; i += stride) p[i] = z;
}

// W_bilin fp32 -> bf16 (same flat layout [i][j][k])
__global__ void wcvt_kernel(const float* __restrict__ w, short* __restrict__ o,
                            int n) {
  int i = blockIdx.x * 256 + threadIdx.x;
  if (i < n) o[i] = f2bf(w[i]);
}

// ---------------------------------------------------------------------------
// w = (rbf @ W_rbf) * silu(m @ W_m + b_m)        [E, EMB]
// v3: 128 threads/block; thread i holds the FULL W_m column i in 128 VGPRs.
// m-row reads are wave-uniform (e is a scalar loop var) -> scalar-cache
// s_load_dwordx4; NO LDS, NO barriers. Inner loop is pure VALU FMA.
// (v2 was LDS-b128-throughput-bound: ~6.4M ds_read_b128 ~= 125 us.)
// ---------------------------------------------------------------------------
__global__ __launch_bounds__(128) void edge_w_kernel(
    const float* __restrict__ rbf, const float* __restrict__ m,
    const float* __restrict__ W_rbf, const float* __restrict__ W_m,
    const float* __restrict__ b_m, float* __restrict__ w_out, int E) {
  const int i = threadIdx.x;  // output column 0..127

  float Wreg[EMB];
#pragma unroll
  for (int k = 0; k < EMB; ++k) Wreg[k] = W_m[k * EMB + i];
  float wr[NR];
#pragma unroll
  for (int r = 0; r < NR; ++r) wr[r] = W_rbf[r * EMB + i];
  const float bm = b_m[i];

  for (int e = blockIdx.x; e < E; e += gridDim.x) {
    const float4* mrow = (const float4*)(m + (long)e * EMB);  // wave-uniform
    float acc = 0.f;
#pragma unroll
    for (int q = 0; q < 32; ++q) {
      float4 mv = mrow[q];  // s_load (uniform) -> broadcast to VALU
      acc += Wreg[q * 4 + 0] * mv.x + Wreg[q * 4 + 1] * mv.y +
             Wreg[q * 4 + 2] * mv.z + Wreg[q * 4 + 3] * mv.w;
    }
    float x = acc + bm;
    float sig = 1.f / (1.f + expf(-x));
    float act = x * sig;
    float ar = 0.f;
#pragma unroll
    for (int r = 0; r < NR; ++r) ar += wr[r] * rbf[(long)e * NR + r];
    w_out[(long)e * EMB + i] = ar * act;
  }
}

// ---------------------------------------------------------------------------
// helper: load one B fragment (16 B) either bf16-direct or fp32+convert
// ---------------------------------------------------------------------------
template <bool WB>
__device__ __forceinline__ short8 ldB(const float* __restrict__ wf,
                                      const short* __restrict__ wh, int off) {
  if (WB) {
    return *(const short8*)(wh + off);
  } else {
    float4 u0 = *(const float4*)(wf + off);
    float4 u1 = *(const float4*)(wf + off + 4);
    short8 h;
    h[0] = f2bf(u0.x); h[1] = f2bf(u0.y); h[2] = f2bf(u0.z); h[3] = f2bf(u0.w);
    h[4] = f2bf(u1.x); h[5] = f2bf(u1.y); h[6] = f2bf(u1.z); h[7] = f2bf(u1.w);
    return h;
  }
}

// ---------------------------------------------------------------------------
// MFMA triplet kernel v4. TL=128, 512 threads = 8 waves.
// Wave wv: wm=wv>>1 owns M-tiles wm*2..+1; wn=wv&1 owns N-tiles wn*4..+3.
// vs v3 (337us):
//  - A frags in REGISTERS (8 frags = 32 VGPR), read from LDS exactly once.
//    Per-j LDS reads drop 42 -> 18 b128/wave (v3 was LDS-issue-bound:
//    ~13us/block of ds_read at 12cyc each).
//  - LDS 70 KB: A-staging region UNIONED with wS[1] (A is consumed into
//    regs before wS[1]'s first write) -> 2 blocks/CU resident; one block's
//    gather head + atomic tail overlap the other's MFMA phase.
//  - launch_bounds(512,4): 128-VGPR cap so 16 waves/CU actually fit.
//  - keeps v3's T14 pipeline: prefetch B(j+1) early, ds_write late,
//    one barrier per j.
// ---------------------------------------------------------------------------
template <bool WB>
__global__ __launch_bounds__(512, 4) void triplet_mfma(
    const float* __restrict__ rbf, const float* __restrict__ m,
    const float* __restrict__ o, const int* __restrict__ lg_src,
    const int* __restrict__ lg_dst, const float* __restrict__ W_sbf,
    const float* __restrict__ W_bilin_f, const short* __restrict__ W_bilin_h,
    float* __restrict__ m_update, int L) {
  __shared__ short wSu[2][2048 * 8];  // 2x32 KB; wSu[1] doubles as A staging
  __shared__ float sSt[NB][TL];       // 4 KB: sbf transposed [j][triplet]
  __shared__ int srcS[TL];
  __shared__ int dstS[TL];

  const int tid = threadIdx.x;
  const int lane = tid & 63;
  const int wv = tid >> 6;
  const long base = (long)blockIdx.x * TL;

  if (tid < TL) {
    long l = base + tid;
    int lc = (l < L) ? (int)l : 0;
    srcS[tid] = lg_src[lc];
    dstS[tid] = (l < L) ? lg_dst[lc] : -1;
  }
  __syncthreads();

  // ---- stage A into wSu[1]: frag order [mt(8)][ks(4)][lane][8] ----
#pragma unroll
  for (int iter = 0; iter < 4; ++iter) {
    int s = iter * 512 + tid;             // slot 0..2047
    int c = s >> 6, l2 = s & 63;
    int mt = c >> 2, ks = c & 3;          // mt 0..7
    int row = mt * 16 + (l2 & 15);        // 0..127
    int k = ks * 32 + (l2 >> 4) * 8;
    const float* src = m + (long)srcS[row] * EMB + k;
    float4 v0 = *(const float4*)src;
    float4 v1 = *(const float4*)(src + 4);
    short8 hh;
    hh[0] = f2bf(v0.x); hh[1] = f2bf(v0.y); hh[2] = f2bf(v0.z); hh[3] = f2bf(v0.w);
    hh[4] = f2bf(v1.x); hh[5] = f2bf(v1.y); hh[6] = f2bf(v1.z); hh[7] = f2bf(v1.w);
    *(short8*)&wSu[1][s * 8] = hh;
  }

  // ---- sbf per triplet (threads 0..127), fp32, transposed store ----
  if (tid < TL) {
    long l = base + tid;
    int lc = (l < L) ? (int)l : 0;
    int src = srcS[tid];
    int dst = lg_dst[lc];
    float r1x = o[src * 3 + 0], r1y = o[src * 3 + 1], r1z = o[src * 3 + 2];
    float r2x = o[dst * 3 + 0], r2y = o[dst * 3 + 1], r2z = o[dst * 3 + 2];
    float dotv = r1x * r2x + r1y * r2y + r1z * r2z;
    float cx = r1y * r2z - r1z * r2y;
    float cy = r1z * r2x - r1x * r2z;
    float cz = r1x * r2y - r1y * r2x;
    float crs = sqrtf(cx * cx + cy * cy + cz * cz);
    float angle = atan2f(crs, dotv);
    float cbf[NS];
#pragma unroll
    for (int s_ = 0; s_ < NS; ++s_) cbf[s_] = cosf(angle * (float)s_);
    float rb[NR];
#pragma unroll
    for (int r = 0; r < NR; ++r) rb[r] = rbf[src * NR + r];
#pragma unroll
    for (int b = 0; b < NB; ++b) {
      float sb = 0.f;
#pragma unroll
      for (int s_ = 0; s_ < NS; ++s_) {
        float t = 0.f;
#pragma unroll
        for (int r = 0; r < NR; ++r)
          t += rb[r] * W_sbf[(s_ * NR + r) * NB + b];
        sb += cbf[s_] * t;
      }
      sSt[b][tid] = sb;
    }
  }

  // ---- per-thread B staging geometry (4 slots: q*512+tid) ----
  // c2 = q*8+wv -> ks=q, nt=wv; offsets fit in int (max ~131k elements)
  int bOff[4];
#pragma unroll
  for (int q = 0; q < 4; ++q) {
    int c2 = (q * 512 + tid) >> 6;
    int ks = c2 >> 3, nt = c2 & 7;
    int i = nt * 16 + (lane & 15);
    int k = ks * 32 + (lane >> 4) * 8;
    bOff[q] = i * (NB * EMB) + k;
  }

  // ---- stage B(j=0) into wSu[0] ----
#pragma unroll
  for (int q = 0; q < 4; ++q)
    *(short8*)&wSu[0][(q * 512 + tid) * 8] =
        ldB<WB>(W_bilin_f, W_bilin_h, bOff[q]);

  __syncthreads();  // A-stage, sbf, B0 all visible

  const int wm = wv >> 1;        // 0..3: M-tiles wm*2, wm*2+1
  const int wn = wv & 1;         // 0..1: N-tiles wn*4..+3
  const int kq = lane >> 4;
  const int col16 = lane & 15;

  // ---- A fragments to registers (read LDS once) ----
  short8 A0[4], A1[4];
#pragma unroll
  for (int ks = 0; ks < 4; ++ks) {
    A0[ks] = *(const short8*)&wSu[1][(((wm * 2 + 0) * 4 + ks) * 64 + lane) * 8];
    A1[ks] = *(const short8*)&wSu[1][(((wm * 2 + 1) * 4 + ks) * 64 + lane) * 8];
  }
  __syncthreads();  // all waves done with wSu[1] -> reusable as B dbuf

  float accf[2][4][4];
#pragma unroll
  for (int mt = 0; mt < 2; ++mt)
#pragma unroll
    for (int nn = 0; nn < 4; ++nn)
#pragma unroll
      for (int r = 0; r < 4; ++r) accf[mt][nn][r] = 0.f;

#pragma unroll 1
  for (int j = 0; j < NB; ++j) {
    const short* wcur = (j & 1) ? &wSu[1][0] : &wSu[0][0];
    short* wnxt = (j & 1) ? &wSu[0][0] : &wSu[1][0];

    // T14 issue-early: prefetch B(j+1) (latency hides under compute(j))
    short8 pre0, pre1, pre2, pre3;
    if (j < NB - 1) {
      const int jo = (j + 1) * EMB;
      pre0 = ldB<WB>(W_bilin_f, W_bilin_h, bOff[0] + jo);
      pre1 = ldB<WB>(W_bilin_f, W_bilin_h, bOff[1] + jo);
      pre2 = ldB<WB>(W_bilin_f, W_bilin_h, bOff[2] + jo);
      pre3 = ldB<WB>(W_bilin_f, W_bilin_h, bOff[3] + jo);
    }

    const floatx4 sv0 = *(const floatx4*)&sSt[j][(wm * 2 + 0) * 16 + kq * 4];
    const floatx4 sv1 = *(const floatx4*)&sSt[j][(wm * 2 + 1) * 16 + kq * 4];

#pragma unroll
    for (int nh = 0; nh < 2; ++nh) {  // N-tile pairs (keeps C at 16 VGPR)
      floatx4 C00 = (floatx4)0.f, C01 = (floatx4)0.f;
      floatx4 C10 = (floatx4)0.f, C11 = (floatx4)0.f;
      const int ntA = wn * 4 + nh * 2;
#pragma unroll
      for (int ks = 0; ks < 4; ++ks) {
        short8 b0 = *(const short8*)&wcur[((ks * 8 + ntA + 0) * 64 + lane) * 8];
        short8 b1 = *(const short8*)&wcur[((ks * 8 + ntA + 1) * 64 + lane) * 8];
        C00 = __builtin_amdgcn_mfma_f32_16x16x32_bf16(A0[ks], b0, C00, 0, 0, 0);
        C01 = __builtin_amdgcn_mfma_f32_16x16x32_bf16(A0[ks], b1, C01, 0, 0, 0);
        C10 = __builtin_amdgcn_mfma_f32_16x16x32_bf16(A1[ks], b0, C10, 0, 0, 0);
        C11 = __builtin_amdgcn_mfma_f32_16x16x32_bf16(A1[ks], b1, C11, 0, 0, 0);
      }
#pragma unroll
      for (int r = 0; r < 4; ++r) {
        accf[0][nh * 2 + 0][r] += sv0[r] * C00[r];
        accf[0][nh * 2 + 1][r] += sv0[r] * C01[r];
        accf[1][nh * 2 + 0][r] += sv1[r] * C10[r];
        accf[1][nh * 2 + 1][r] += sv1[r] * C11[r];
      }
    }

    // write-late: prefetched B(j+1) -> wnxt (its readers finished at the
    // previous barrier)
    if (j < NB - 1) {
      *(short8*)&wnxt[(0 * 512 + tid) * 8] = pre0;
      *(short8*)&wnxt[(1 * 512 + tid) * 8] = pre1;
      *(short8*)&wnxt[(2 * 512 + tid) * 8] = pre2;
      *(short8*)&wnxt[(3 * 512 + tid) * 8] = pre3;
    }
    __syncthreads();  // one barrier per j
  }

  // ---- scatter-add into m_update ----
#pragma unroll
  for (int mt = 0; mt < 2; ++mt) {
#pragma unroll
    for (int r = 0; r < 4; ++r) {
      int row = (wm * 2 + mt) * 16 + kq * 4 + r;
      int dst = dstS[row];
      if (dst >= 0) {
        float* p = m_update + (long)dst * EMB + col16;
#pragma unroll
        for (int nt = 0; nt < 4; ++nt)
          unsafeAtomicAdd(p + (wn * 4 + nt) * 16, accf[mt][nt][r]);
      }
    }
  }
}

// ---------------------------------------------------------------------------
extern "C" void kernel_launch(void* const* d_in, const int* in_sizes, int n_in,
                              void* d_out, int out_size, void* d_ws,
                              size_t ws_size, hipStream_t stream) {
  const float* rbf = (const float*)d_in[0];
  const float* m = (const float*)d_in[1];
  const float* o = (const float*)d_in[2];
  const int* lg_src = (const int*)d_in[3];
  const int* lg_dst = (const int*)d_in[4];
  const float* W_rbf = (const float*)d_in[5];
  const float* W_m = (const float*)d_in[6];
  const float* b_m = (const float*)d_in[7];
  const float* W_sbf = (const float*)d_in[8];
  const float* W_bilin = (const float*)d_in[9];

  const int E = in_sizes[1] / EMB;
  const int L = in_sizes[3];

  float* w_out = (float*)d_out;
  float* m_update = (float*)d_out + (long)E * EMB;

  long n4 = (long)E * EMB / 4;
  zero_kernel<<<2048, 256, 0, stream>>>((float4*)m_update, n4);
  edge_w_kernel<<<4096, 128, 0, stream>>>(rbf, m, W_rbf, W_m, b_m, w_out, E);

  int nblk = (L + TL - 1) / TL;
  const int wn = EMB * NB * EMB;  // 131072
  if (ws_size >= (size_t)wn * sizeof(short)) {
    short* wh = (short*)d_ws;
    wcvt_kernel<<<(wn + 255) / 256, 256, 0, stream>>>(W_bilin, wh, wn);
    triplet_mfma<true><<<nblk, 512, 0, stream>>>(
        rbf, m, o, lg_src, lg_dst, W_sbf, nullptr, wh, m_update, L);
  } else {
    triplet_mfma<false><<<nblk, 512, 0, stream>>>(
        rbf, m, o, lg_src, lg_dst, W_sbf, W_bilin, nullptr, m_update, L);
  }
}

// Round 5
// 554.914 us; speedup vs baseline: 1.4006x; 1.4006x over previous
//
#include <hip/hip_runtime.h>
#include <math.h>

#define EMB 128
#define NR 6
#define NS 7
#define NB 8
#define TL 256   // triplets per block in the MFMA bilinear kernel

typedef __attribute__((ext_vector_type(8))) short short8;   // 8 bf16 = 4 VGPR
typedef __attribute__((ext_vector_type(4))) float floatx4;  // MFMA C/D

__device__ __forceinline__ short f2bf(float f) {  // fp32 -> bf16 RNE
  unsigned int u = __float_as_uint(f);
  u = u + 0x7fff + ((u >> 16) & 1);
  return (short)(u >> 16);
}

// ---------------------------------------------------------------------------
__global__ void zero_kernel(float4* __restrict__ p, long n4) {
  long i = (long)blockIdx.x * blockDim.x + threadIdx.x;
  long stride = (long)gridDim.x * blockDim.x;
  float4 z; z.x = z.y = z.z = z.w = 0.f;
  for (; i < n4; i += stride) p[i] = z;
}

// W_bilin fp32 -> bf16 (same flat layout [i][j][k])
__global__ void wcvt_kernel(const float* __restrict__ w, short* __restrict__ o,
                            int n) {
  int i = blockIdx.x * 256 + threadIdx.x;
  if (i < n) o[i] = f2bf(w[i]);
}

// ---------------------------------------------------------------------------
// w = (rbf @ W_rbf) * silu(m @ W_m + b_m)   [E, EMB]  -- MFMA version.
// 512 threads = 8 waves; wave wv owns N-tile wv (cols wv*16..+15).
// W_m B-fragments: 16 VGPR/wave, loaded ONCE (column-strided scalar loads,
// W_m is L2-hot). m rows are CONTIGUOUS -> A-fragments load direct from
// global (lanes {r,r+16,r+32,r+48} cover a full 128B line). Zero LDS, zero
// barriers. 64 rows per iteration, 16 MFMA + epilogue (silu + rbf matvec).
// v3's scalar-broadcast version was a dependent-FMA latency chain (~360us);
// v2's LDS version was ds_read-throughput-bound (~200us).
// ---------------------------------------------------------------------------
__global__ __launch_bounds__(512) void edge_w_mfma(
    const float* __restrict__ rbf, const float* __restrict__ m,
    const float* __restrict__ W_rbf, const float* __restrict__ W_m,
    const float* __restrict__ b_m, float* __restrict__ w_out, int E) {
  const int tid = threadIdx.x;
  const int lane = tid & 63;
  const int nt = tid >> 6;        // wave id = N-tile 0..7
  const int col16 = lane & 15;
  const int kq = lane >> 4;
  const int col = nt * 16 + col16;

  // B fragments of W_m: lane holds W_m[k][col], k = ks*32 + kq*8 + q
  short8 Bw[4];
#pragma unroll
  for (int ks = 0; ks < 4; ++ks) {
    short8 h;
#pragma unroll
    for (int q = 0; q < 8; ++q)
      h[q] = f2bf(W_m[(ks * 32 + kq * 8 + q) * EMB + col]);
    Bw[ks] = h;
  }
  float wrbf[NR];
#pragma unroll
  for (int r = 0; r < NR; ++r) wrbf[r] = W_rbf[r * EMB + col];
  const float bm = b_m[col];

  for (long e0 = (long)blockIdx.x * 64; e0 < E; e0 += (long)gridDim.x * 64) {
    // ---- A fragments for 4 M-tiles, direct global->reg (rows contiguous) --
    short8 Af[4][4];
#pragma unroll
    for (int mt = 0; mt < 4; ++mt) {
      long row = e0 + mt * 16 + col16;
      if (row >= E) row = E - 1;  // tail clamp (stores are guarded below)
      const float* src = m + row * EMB;
#pragma unroll
      for (int ks = 0; ks < 4; ++ks) {
        float4 v0 = *(const float4*)(src + ks * 32 + kq * 8);
        float4 v1 = *(const float4*)(src + ks * 32 + kq * 8 + 4);
        short8 h;
        h[0] = f2bf(v0.x); h[1] = f2bf(v0.y); h[2] = f2bf(v0.z); h[3] = f2bf(v0.w);
        h[4] = f2bf(v1.x); h[5] = f2bf(v1.y); h[6] = f2bf(v1.z); h[7] = f2bf(v1.w);
        Af[mt][ks] = h;
      }
    }
    // ---- GEMM: 16 MFMA ----
    floatx4 acc[4];
#pragma unroll
    for (int mt = 0; mt < 4; ++mt) {
      acc[mt] = (floatx4)0.f;
#pragma unroll
      for (int ks = 0; ks < 4; ++ks)
        acc[mt] = __builtin_amdgcn_mfma_f32_16x16x32_bf16(Af[mt][ks], Bw[ks],
                                                          acc[mt], 0, 0, 0);
    }
    // ---- epilogue: silu + (rbf @ W_rbf) scale, store ----
#pragma unroll
    for (int mt = 0; mt < 4; ++mt) {
#pragma unroll
      for (int r = 0; r < 4; ++r) {
        long row = e0 + mt * 16 + kq * 4 + r;
        if (row < E) {
          float x = acc[mt][r] + bm;
          float sig = 1.f / (1.f + expf(-x));
          float ar = 0.f;
#pragma unroll
          for (int rr = 0; rr < NR; ++rr)
            ar += rbf[row * NR + rr] * wrbf[rr];  // 16-lane broadcast via L1
          w_out[row * EMB + col] = ar * x * sig;
        }
      }
    }
  }
}

// ---------------------------------------------------------------------------
// helper: load one B fragment (16 B) either bf16-direct or fp32+convert
// ---------------------------------------------------------------------------
template <bool WB>
__device__ __forceinline__ short8 ldB(const float* __restrict__ wf,
                                      const short* __restrict__ wh, int off) {
  if (WB) {
    return *(const short8*)(wh + off);
  } else {
    float4 u0 = *(const float4*)(wf + off);
    float4 u1 = *(const float4*)(wf + off + 4);
    short8 h;
    h[0] = f2bf(u0.x); h[1] = f2bf(u0.y); h[2] = f2bf(u0.z); h[3] = f2bf(u0.w);
    h[4] = f2bf(u1.x); h[5] = f2bf(u1.y); h[6] = f2bf(u1.z); h[7] = f2bf(u1.w);
    return h;
  }
}

// ---------------------------------------------------------------------------
// MFMA triplet kernel v5. TL=256, 512 threads = 8 waves.
// Wave wv: wm=wv>>1 owns M-tiles wm*4..+3; wn=wv&1 owns N-tiles wn*4..+3.
// vs v3 (337us, round-2 verified):
//  - A frags PINNED in registers (16 frags = 64 VGPR, read from LDS once).
//    Per-j LDS reads: 42 -> 20 b128/wave.
//  - A-staging LDS region unioned with the B double-buffer (A consumed into
//    regs, with a barrier, before wS[0] is first written): LDS 138 -> 74 KB.
//  - launch_bounds(512, 2): 256-VGPR cap. NOT (512,4) -- v4 showed the
//    128-cap forces spills (VGPR_Count=64, WRITE +171MB scratch traffic).
//  - keeps v3's T14 pipeline: prefetch B(j+1) early, ds_write late,
//    one barrier per j; keeps v3's TL=256 atomic/L2 pattern (WRITE=250MB).
// ---------------------------------------------------------------------------
template <bool WB>
__global__ __launch_bounds__(512, 2) void triplet_mfma(
    const float* __restrict__ rbf, const float* __restrict__ m,
    const float* __restrict__ o, const int* __restrict__ lg_src,
    const int* __restrict__ lg_dst, const float* __restrict__ W_sbf,
    const float* __restrict__ W_bilin_f, const short* __restrict__ W_bilin_h,
    float* __restrict__ m_update, int L) {
  __shared__ short wSu[2][2048 * 8];  // 64 KB; full region doubles as A stage
  __shared__ float sSt[NB][TL];       // 8 KB: sbf transposed [j][triplet]
  __shared__ int srcS[TL];
  __shared__ int dstS[TL];

  const int tid = threadIdx.x;
  const int lane = tid & 63;
  const int wv = tid >> 6;
  const long base = (long)blockIdx.x * TL;
  short* aSu = &wSu[0][0];  // flat 4096-slot view for A staging

  if (tid < TL) {
    long l = base + tid;
    int lc = (l < L) ? (int)l : 0;
    srcS[tid] = lg_src[lc];
    dstS[tid] = (l < L) ? lg_dst[lc] : -1;
  }
  __syncthreads();

  // ---- stage A into union region: frag order [mtG(16)][ks(4)][lane][8] ----
#pragma unroll
  for (int iter = 0; iter < 8; ++iter) {
    int s = iter * 512 + tid;             // slot 0..4095
    int c = s >> 6, l2 = s & 63;
    int mt = c >> 2, ks = c & 3;          // mtG 0..15
    int row = mt * 16 + (l2 & 15);        // 0..255
    int k = ks * 32 + (l2 >> 4) * 8;
    const float* src = m + (long)srcS[row] * EMB + k;
    float4 v0 = *(const float4*)src;
    float4 v1 = *(const float4*)(src + 4);
    short8 hh;
    hh[0] = f2bf(v0.x); hh[1] = f2bf(v0.y); hh[2] = f2bf(v0.z); hh[3] = f2bf(v0.w);
    hh[4] = f2bf(v1.x); hh[5] = f2bf(v1.y); hh[6] = f2bf(v1.z); hh[7] = f2bf(v1.w);
    *(short8*)&aSu[s * 8] = hh;
  }

  // ---- sbf per triplet (threads 0..255), fp32, transposed store ----
  if (tid < TL) {
    long l = base + tid;
    int lc = (l < L) ? (int)l : 0;
    int src = srcS[tid];
    int dst = lg_dst[lc];
    float r1x = o[src * 3 + 0], r1y = o[src * 3 + 1], r1z = o[src * 3 + 2];
    float r2x = o[dst * 3 + 0], r2y = o[dst * 3 + 1], r2z = o[dst * 3 + 2];
    float dotv = r1x * r2x + r1y * r2y + r1z * r2z;
    float cx = r1y * r2z - r1z * r2y;
    float cy = r1z * r2x - r1x * r2z;
    float cz = r1x * r2y - r1y * r2x;
    float crs = sqrtf(cx * cx + cy * cy + cz * cz);
    float angle = atan2f(crs, dotv);
    float cbf[NS];
#pragma unroll
    for (int s_ = 0; s_ < NS; ++s_) cbf[s_] = cosf(angle * (float)s_);
    float rb[NR];
#pragma unroll
    for (int r = 0; r < NR; ++r) rb[r] = rbf[src * NR + r];
#pragma unroll
    for (int b = 0; b < NB; ++b) {
      float sb = 0.f;
#pragma unroll
      for (int s_ = 0; s_ < NS; ++s_) {
        float t = 0.f;
#pragma unroll
        for (int r = 0; r < NR; ++r)
          t += rb[r] * W_sbf[(s_ * NR + r) * NB + b];
        sb += cbf[s_] * t;
      }
      sSt[b][tid] = sb;
    }
  }
  __syncthreads();  // A-stage + sbf visible

  const int wm = wv >> 1;        // 0..3: M-tiles wm*4..+3
  const int wn = wv & 1;         // 0..1: N-tiles wn*4..+3
  const int kq = lane >> 4;
  const int col16 = lane & 15;

  // ---- A fragments to registers (read LDS once; 64 VGPR) ----
  short8 Areg[4][4];
#pragma unroll
  for (int mt = 0; mt < 4; ++mt)
#pragma unroll
    for (int ks = 0; ks < 4; ++ks)
      Areg[mt][ks] =
          *(const short8*)&aSu[(((wm * 4 + mt) * 4 + ks) * 64 + lane) * 8];
  __syncthreads();  // all waves done reading A -> region reusable as B dbuf

  // ---- per-thread B staging geometry (4 slots: q*512+tid) ----
  int bOff[4];
#pragma unroll
  for (int q = 0; q < 4; ++q) {
    int c2 = (q * 512 + tid) >> 6;
    int ks = c2 >> 3, nt = c2 & 7;
    int i = nt * 16 + (lane & 15);
    int k = ks * 32 + (lane >> 4) * 8;
    bOff[q] = i * (NB * EMB) + k;
  }

  // ---- stage B(j=0) into wSu[0] ----
#pragma unroll
  for (int q = 0; q < 4; ++q)
    *(short8*)&wSu[0][(q * 512 + tid) * 8] =
        ldB<WB>(W_bilin_f, W_bilin_h, bOff[q]);
  __syncthreads();

  float accf[4][4][4];  // [mt][nt-local][r]
#pragma unroll
  for (int mt = 0; mt < 4; ++mt)
#pragma unroll
    for (int nn = 0; nn < 4; ++nn)
#pragma unroll
      for (int r = 0; r < 4; ++r) accf[mt][nn][r] = 0.f;

#pragma unroll 1
  for (int j = 0; j < NB; ++j) {
    const short* wcur = (j & 1) ? &wSu[1][0] : &wSu[0][0];
    short* wnxt = (j & 1) ? &wSu[0][0] : &wSu[1][0];

    // T14 issue-early: prefetch B(j+1) (latency hides under compute(j))
    short8 pre0, pre1, pre2, pre3;
    if (j < NB - 1) {
      const int jo = (j + 1) * EMB;
      pre0 = ldB<WB>(W_bilin_f, W_bilin_h, bOff[0] + jo);
      pre1 = ldB<WB>(W_bilin_f, W_bilin_h, bOff[1] + jo);
      pre2 = ldB<WB>(W_bilin_f, W_bilin_h, bOff[2] + jo);
      pre3 = ldB<WB>(W_bilin_f, W_bilin_h, bOff[3] + jo);
    }

    floatx4 sv[4];
#pragma unroll
    for (int mt = 0; mt < 4; ++mt)
      sv[mt] = *(const floatx4*)&sSt[j][(wm * 4 + mt) * 16 + kq * 4];

#pragma unroll
    for (int nh = 0; nh < 2; ++nh) {  // N-tile pairs
      const int ntA = wn * 4 + nh * 2;
      short8 Bf0[4], Bf1[4];
#pragma unroll
      for (int ks = 0; ks < 4; ++ks) {
        Bf0[ks] = *(const short8*)&wcur[((ks * 8 + ntA + 0) * 64 + lane) * 8];
        Bf1[ks] = *(const short8*)&wcur[((ks * 8 + ntA + 1) * 64 + lane) * 8];
      }
#pragma unroll
      for (int mt = 0; mt < 4; ++mt) {
        floatx4 C0 = (floatx4)0.f, C1 = (floatx4)0.f;
#pragma unroll
        for (int ks = 0; ks < 4; ++ks) {
          C0 = __builtin_amdgcn_mfma_f32_16x16x32_bf16(Areg[mt][ks], Bf0[ks],
                                                       C0, 0, 0, 0);
          C1 = __builtin_amdgcn_mfma_f32_16x16x32_bf16(Areg[mt][ks], Bf1[ks],
                                                       C1, 0, 0, 0);
        }
#pragma unroll
        for (int r = 0; r < 4; ++r) {
          accf[mt][nh * 2 + 0][r] += sv[mt][r] * C0[r];
          accf[mt][nh * 2 + 1][r] += sv[mt][r] * C1[r];
        }
      }
    }

    // write-late: prefetched B(j+1) -> wnxt
    if (j < NB - 1) {
      *(short8*)&wnxt[(0 * 512 + tid) * 8] = pre0;
      *(short8*)&wnxt[(1 * 512 + tid) * 8] = pre1;
      *(short8*)&wnxt[(2 * 512 + tid) * 8] = pre2;
      *(short8*)&wnxt[(3 * 512 + tid) * 8] = pre3;
    }
    __syncthreads();  // one barrier per j
  }

  // ---- scatter-add into m_update ----
#pragma unroll
  for (int mt = 0; mt < 4; ++mt) {
#pragma unroll
    for (int r = 0; r < 4; ++r) {
      int row = (wm * 4 + mt) * 16 + kq * 4 + r;
      int dst = dstS[row];
      if (dst >= 0) {
        float* p = m_update + (long)dst * EMB + col16;
#pragma unroll
        for (int nt = 0; nt < 4; ++nt)
          unsafeAtomicAdd(p + (wn * 4 + nt) * 16, accf[mt][nt][r]);
      }
    }
  }
}

// ---------------------------------------------------------------------------
extern "C" void kernel_launch(void* const* d_in, const int* in_sizes, int n_in,
                              void* d_out, int out_size, void* d_ws,
                              size_t ws_size, hipStream_t stream) {
  const float* rbf = (const float*)d_in[0];
  const float* m = (const float*)d_in[1];
  const float* o = (const float*)d_in[2];
  const int* lg_src = (const int*)d_in[3];
  const int* lg_dst = (const int*)d_in[4];
  const float* W_rbf = (const float*)d_in[5];
  const float* W_m = (const float*)d_in[6];
  const float* b_m = (const float*)d_in[7];
  const float* W_sbf = (const float*)d_in[8];
  const float* W_bilin = (const float*)d_in[9];

  const int E = in_sizes[1] / EMB;
  const int L = in_sizes[3];

  float* w_out = (float*)d_out;
  float* m_update = (float*)d_out + (long)E * EMB;

  long n4 = (long)E * EMB / 4;
  zero_kernel<<<2048, 256, 0, stream>>>((float4*)m_update, n4);
  edge_w_mfma<<<782, 512, 0, stream>>>(rbf, m, W_rbf, W_m, b_m, w_out, E);

  int nblk = (L + TL - 1) / TL;
  const int wn = EMB * NB * EMB;  // 131072
  if (ws_size >= (size_t)wn * sizeof(short)) {
    short* wh = (short*)d_ws;
    wcvt_kernel<<<(wn + 255) / 256, 256, 0, stream>>>(W_bilin, wh, wn);
    triplet_mfma<true><<<nblk, 512, 0, stream>>>(
        rbf, m, o, lg_src, lg_dst, W_sbf, nullptr, wh, m_update, L);
  } else {
    triplet_mfma<false><<<nblk, 512, 0, stream>>>(
        rbf, m, o, lg_src, lg_dst, W_sbf, W_bilin, nullptr, m_update, L);
  }
}